// Round 1
// baseline (2280.860 us; speedup 1.0000x reference)
//
#include <hip/hip_runtime.h>
#include <math.h>

#define BB 8
#define CC 64
#define HH 128
#define WW 128
#define EE 8
#define OO 64
#define HID 128
#define GATEC 96
#define NP 8     // patches per spatial dim
#define PP 16    // patch size
#define CH 16    // channels staged in LDS per chunk

// ---------------- Kernel A: router gates ----------------
// one block per (b, pi, pj); 256 threads
__global__ __launch_bounds__(256) void gate_kernel(
    const float* __restrict__ x,
    const float* __restrict__ W1, const float* __restrict__ b1,
    const float* __restrict__ W2, const float* __restrict__ b2,
    float* __restrict__ probs) {
  int blk = blockIdx.x;        // b*64 + pi*8 + pj
  int b  = blk >> 6;
  int pi = (blk >> 3) & 7;
  int pj = blk & 7;
  int t  = threadIdx.x;

  __shared__ float ps[256];
  __shared__ float g[GATEC];
  __shared__ float hbuf[HID];
  __shared__ float lg[EE];

  // --- patch mean pooling: thread t handles channel t/4, row-quarter t%4 ---
  {
    int c = t >> 2, q = t & 3;
    const float* xb = x + ((size_t)(b * CC + c) * HH + pi * PP + q * 4) * WW + pj * PP;
    float s = 0.f;
    for (int r = 0; r < 4; ++r)
      for (int col = 0; col < PP; ++col)
        s += xb[r * WW + col];
    ps[t] = s;
  }
  __syncthreads();
  if (t < CC) {
    g[t] = (ps[4*t] + ps[4*t+1] + ps[4*t+2] + ps[4*t+3]) * (1.f / 256.f);
  } else if (t < CC + 32) {
    // fourier features: channels 64 + kind*8 + fi
    int k = t - CC;
    int fi = k & 7, kind = k >> 3;
    float freq  = (float)(1 << fi);
    float coord = (kind < 2) ? ((pi + 0.5f) / 8.f) : ((pj + 0.5f) / 8.f);
    float a = 6.28318530717958647692f * freq * coord;
    g[t] = (kind & 1) ? cosf(a) : sinf(a);
  }
  __syncthreads();
  // --- MLP layer 1 ---
  if (t < HID) {
    float acc = b1[t];
    const float* w = W1 + (size_t)t * GATEC;
    for (int c = 0; c < GATEC; ++c) acc += w[c] * g[c];
    hbuf[t] = fmaxf(acc, 0.f);
  }
  __syncthreads();
  // --- MLP layer 2 ---
  if (t < EE) {
    float acc = b2[t];
    const float* w = W2 + (size_t)t * HID;
    for (int k = 0; k < HID; ++k) acc += w[k] * hbuf[k];
    lg[t] = acc;
  }
  __syncthreads();
  // --- softmax over E (each of 8 threads redundantly reduces; trivial) ---
  if (t < EE) {
    float m = lg[0];
    for (int e = 1; e < EE; ++e) m = fmaxf(m, lg[e]);
    float sum = 0.f;
    for (int e = 0; e < EE; ++e) sum += expf(lg[e] - m);
    probs[((size_t)(b * EE + t) * NP + pi) * NP + pj] = expf(lg[t] - m) / sum;
  }
}

// ---------------- Kernel B: fused expert conv + gated combine ----------------
// grid: (64 tiles, B, 2 o-halves); 256 threads = one 16x16 pixel tile
__global__ __launch_bounds__(256) void conv_moe(
    const float* __restrict__ x,
    const float* __restrict__ We, const float* __restrict__ be,
    const float* __restrict__ probs, float* __restrict__ out) {
  int tile = blockIdx.x;           // pi*8 + pj
  int b    = blockIdx.y;
  int oh   = blockIdx.z;           // 0..1 -> output channels oh*32 .. +31
  int pi = tile >> 3, pj = tile & 7;
  int ty = threadIdx.x >> 4, tx = threadIdx.x & 15;

  __shared__ float xs[CH][18][18];

  float gate[EE];
#pragma unroll
  for (int e = 0; e < EE; ++e)
    gate[e] = probs[((size_t)(b * EE + e) * NP + pi) * NP + pj];

  float outacc[32];
#pragma unroll
  for (int o = 0; o < 32; ++o) outacc[o] = 0.f;

  const int h0 = pi * PP, w0 = pj * PP;

  for (int e = 0; e < EE; ++e) {
    float acc[32];
#pragma unroll
    for (int o = 0; o < 32; ++o) acc[o] = 0.f;

    for (int c0 = 0; c0 < CC; c0 += CH) {
      __syncthreads();
      // stage x[b, c0..c0+CH, h0-1..h0+16, w0-1..w0+16] with zero border pad
      for (int idx = threadIdx.x; idx < CH * 18 * 18; idx += 256) {
        int c   = idx / 324;
        int rem = idx - c * 324;
        int r   = rem / 18;
        int col = rem - r * 18;
        int gr = h0 + r - 1, gc = w0 + col - 1;
        float v = 0.f;
        if (gr >= 0 && gr < HH && gc >= 0 && gc < WW)
          v = x[((size_t)(b * CC + c0 + c) * HH + gr) * WW + gc];
        xs[c][r][col] = v;
      }
      __syncthreads();

      for (int c = 0; c < CH; ++c) {
        float x00 = xs[c][ty    ][tx    ], x01 = xs[c][ty    ][tx + 1], x02 = xs[c][ty    ][tx + 2];
        float x10 = xs[c][ty + 1][tx    ], x11 = xs[c][ty + 1][tx + 1], x12 = xs[c][ty + 1][tx + 2];
        float x20 = xs[c][ty + 2][tx    ], x21 = xs[c][ty + 2][tx + 1], x22 = xs[c][ty + 2][tx + 2];
        // weights: uniform across lanes -> scalar loads
        const float* wp = We + ((size_t)(e * OO + oh * 32) * CC + (c0 + c)) * 9;
#pragma unroll
        for (int o = 0; o < 32; ++o) {
          const float* wo = wp + (size_t)o * CC * 9;
          acc[o] += wo[0] * x00 + wo[1] * x01 + wo[2] * x02
                  + wo[3] * x10 + wo[4] * x11 + wo[5] * x12
                  + wo[6] * x20 + wo[7] * x21 + wo[8] * x22;
        }
      }
    }
    // epilogue for expert e: bias + relu + gate-weighted accumulate
    float gt = gate[e];
#pragma unroll
    for (int o = 0; o < 32; ++o) {
      float v = acc[o] + be[e * OO + oh * 32 + o];
      outacc[o] += gt * fmaxf(v, 0.f);
    }
  }

  int hh = h0 + ty, ww = w0 + tx;
#pragma unroll
  for (int o = 0; o < 32; ++o)
    out[((size_t)(b * OO + oh * 32 + o) * HH + hh) * WW + ww] = outacc[o];
}

extern "C" void kernel_launch(void* const* d_in, const int* in_sizes, int n_in,
                              void* d_out, int out_size, void* d_ws, size_t ws_size,
                              hipStream_t stream) {
  const float* x  = (const float*)d_in[0];
  const float* We = (const float*)d_in[1];
  const float* be = (const float*)d_in[2];
  const float* W1 = (const float*)d_in[3];
  const float* b1 = (const float*)d_in[4];
  const float* W2 = (const float*)d_in[5];
  const float* b2 = (const float*)d_in[6];
  float* out   = (float*)d_out;
  float* probs = (float*)d_ws;   // B*E*8*8 = 4096 floats

  gate_kernel<<<dim3(BB * NP * NP), dim3(256), 0, stream>>>(x, W1, b1, W2, b2, probs);
  conv_moe<<<dim3(NP * NP, BB, 2), dim3(256), 0, stream>>>(x, We, be, probs, out);
}

// Round 2
// 213.011 us; speedup vs baseline: 10.7077x; 10.7077x over previous
//
#include <hip/hip_runtime.h>
#include <math.h>

#define BB 8
#define CC 64
#define HH 128
#define WW 128
#define EE 8
#define OO 64
#define HID 128
#define GATEC 96
#define NP 8     // patches per spatial dim
#define PP 16    // patch size

typedef __attribute__((ext_vector_type(8))) short bf16x8;
typedef __attribute__((ext_vector_type(4))) float f32x4;

static __device__ __forceinline__ unsigned short f2bf(float f) {
  unsigned int u = __builtin_bit_cast(unsigned int, f);
  unsigned int r = (u + 0x7FFFu + ((u >> 16) & 1u)) >> 16;   // RNE
  return (unsigned short)r;
}

// ---------------- Kernel A: router gates (f32, unchanged) ----------------
__global__ __launch_bounds__(256) void gate_kernel(
    const float* __restrict__ x,
    const float* __restrict__ W1, const float* __restrict__ b1,
    const float* __restrict__ W2, const float* __restrict__ b2,
    float* __restrict__ probs) {
  int blk = blockIdx.x;        // b*64 + pi*8 + pj
  int b  = blk >> 6;
  int pi = (blk >> 3) & 7;
  int pj = blk & 7;
  int t  = threadIdx.x;

  __shared__ float ps[256];
  __shared__ float g[GATEC];
  __shared__ float hbuf[HID];
  __shared__ float lg[EE];

  {
    int c = t >> 2, q = t & 3;
    const float* xb = x + ((size_t)(b * CC + c) * HH + pi * PP + q * 4) * WW + pj * PP;
    float s = 0.f;
    for (int r = 0; r < 4; ++r)
      for (int col = 0; col < PP; ++col)
        s += xb[r * WW + col];
    ps[t] = s;
  }
  __syncthreads();
  if (t < CC) {
    g[t] = (ps[4*t] + ps[4*t+1] + ps[4*t+2] + ps[4*t+3]) * (1.f / 256.f);
  } else if (t < CC + 32) {
    int k = t - CC;
    int fi = k & 7, kind = k >> 3;
    float freq  = (float)(1 << fi);
    float coord = (kind < 2) ? ((pi + 0.5f) / 8.f) : ((pj + 0.5f) / 8.f);
    float a = 6.28318530717958647692f * freq * coord;
    g[t] = (kind & 1) ? cosf(a) : sinf(a);
  }
  __syncthreads();
  if (t < HID) {
    float acc = b1[t];
    const float* w = W1 + (size_t)t * GATEC;
    for (int c = 0; c < GATEC; ++c) acc += w[c] * g[c];
    hbuf[t] = fmaxf(acc, 0.f);
  }
  __syncthreads();
  if (t < EE) {
    float acc = b2[t];
    const float* w = W2 + (size_t)t * HID;
    for (int k = 0; k < HID; ++k) acc += w[k] * hbuf[k];
    lg[t] = acc;
  }
  __syncthreads();
  if (t < EE) {
    float m = lg[0];
    for (int e = 1; e < EE; ++e) m = fmaxf(m, lg[e]);
    float sum = 0.f;
    for (int e = 0; e < EE; ++e) sum += expf(lg[e] - m);
    probs[((size_t)(b * EE + t) * NP + pi) * NP + pj] = expf(lg[t] - m) / sum;
  }
}

// ---------------- Kernel P: pack weights f32 [e][o][c][3][3] -> bf16 [e][t][o][c] ---
__global__ __launch_bounds__(256) void pack_kernel(
    const float* __restrict__ We, unsigned short* __restrict__ wp) {
  int idx = blockIdx.x * 256 + threadIdx.x;
  if (idx >= EE * 9 * OO * CC) return;
  int c  = idx & 63;
  int o  = (idx >> 6) & 63;
  int et = idx >> 12;            // e*9 + t
  int t  = et % 9;
  int e  = et / 9;
  float v = We[(((size_t)(e * OO + o) * CC) + c) * 9 + t];
  wp[idx] = f2bf(v);
}

// ---------------- Kernel B: MFMA expert conv + gated combine ----------------
// block = (b, 16x16 patch); 4 waves; wave w covers pixel rows w*4..w*4+3, all 64 o.
// D = A(weights 16o x 32c) * B(x 32c x 16px): D row=o=(l>>4)*4+r, col=px=l&15.
__global__ __launch_bounds__(256, 2) void conv_moe(
    const float* __restrict__ x,
    const unsigned short* __restrict__ wp,   // [e][t][o][c] bf16
    const float* __restrict__ be,
    const float* __restrict__ probs, float* __restrict__ out) {
  int tile = blockIdx.x;           // pi*8 + pj
  int b    = blockIdx.y;
  int pi = tile >> 3, pj = tile & 7;
  const int h0 = pi * PP, w0 = pj * PP;

  int lane = threadIdx.x & 63;
  int wave = threadIdx.x >> 6;
  int px   = lane & 15;
  int kg   = lane >> 4;            // k-group 0..3
  int w4   = wave * 4;             // this wave's pixel-row base

  // x tile staged as bf16: xs[spatial=18*18][c=64], 16B-slot XOR swizzle by spatial&7
  __shared__ char xs[324 * 128];

  // ---- stage x (once), spatial-fastest for coalesced global reads ----
  for (int idx = threadIdx.x; idx < 324 * 32; idx += 256) {
    int spatial = idx % 324;           // row*18+col in halo tile
    int cp      = idx / 324;           // channel pair 0..31
    int row = spatial / 18, col = spatial % 18;
    int gr = h0 + row - 1, gc = w0 + col - 1;
    int c = cp * 2;
    float v0 = 0.f, v1 = 0.f;
    if (gr >= 0 && gr < HH && gc >= 0 && gc < WW) {
      const float* xb = x + ((size_t)(b * CC + c) * HH + gr) * WW + gc;
      v0 = xb[0];
      v1 = xb[(size_t)HH * WW];
    }
    unsigned int pkd = (unsigned int)f2bf(v0) | ((unsigned int)f2bf(v1) << 16);
    int cbyte = cp * 4;                // byte offset of this c-pair within the 128B row
    int swz   = (cbyte & 15) | ((((cbyte >> 4) ^ (spatial & 7)) & 7) << 4);
    *(unsigned int*)(xs + spatial * 128 + swz) = pkd;
  }
  __syncthreads();

  f32x4 outacc[4][4];
#pragma unroll
  for (int ot = 0; ot < 4; ++ot)
#pragma unroll
    for (int pt = 0; pt < 4; ++pt)
      outacc[ot][pt] = (f32x4)(0.f);

  for (int e = 0; e < EE; ++e) {
    f32x4 acc[4][4];
#pragma unroll
    for (int ot = 0; ot < 4; ++ot)
#pragma unroll
      for (int pt = 0; pt < 4; ++pt)
        acc[ot][pt] = (f32x4)(0.f);

    const unsigned short* wpe = wp + (size_t)e * 9 * OO * CC + px * CC + kg * 8;
    // NOTE: A-operand lane mapping: o = lane&15 (=px var), k = kg*8+j

    for (int t9 = 0; t9 < 9; ++t9) {
      int dy = t9 / 3, dx = t9 - dy * 3;
      const unsigned short* wpt = wpe + t9 * (OO * CC);
      int sB = (w4 + dy) * 18 + px + dx;   // spatial for pt=0
#pragma unroll
      for (int ks = 0; ks < 2; ++ks) {
        bf16x8 aw[4], bx[4];
#pragma unroll
        for (int ot = 0; ot < 4; ++ot)
          aw[ot] = *(const bf16x8*)(wpt + ot * 16 * CC + ks * 32);
#pragma unroll
        for (int pt = 0; pt < 4; ++pt) {
          int sp   = sB + pt * 18;
          int slot = ((ks << 2) + kg) ^ (sp & 7);
          bx[pt] = *(const bf16x8*)(xs + sp * 128 + slot * 16);
        }
#pragma unroll
        for (int ot = 0; ot < 4; ++ot)
#pragma unroll
          for (int pt = 0; pt < 4; ++pt)
            acc[ot][pt] = __builtin_amdgcn_mfma_f32_16x16x32_bf16(
                aw[ot], bx[pt], acc[ot][pt], 0, 0, 0);
      }
    }

    // epilogue: bias + relu + gate-weighted accumulate
    float gt = probs[((size_t)(b * EE + e) * NP + pi) * NP + pj];
#pragma unroll
    for (int ot = 0; ot < 4; ++ot) {
      f32x4 bias = *(const f32x4*)(be + e * OO + ot * 16 + kg * 4);
#pragma unroll
      for (int pt = 0; pt < 4; ++pt) {
#pragma unroll
        for (int r = 0; r < 4; ++r)
          outacc[ot][pt][r] += gt * fmaxf(acc[ot][pt][r] + bias[r], 0.f);
      }
    }
  }

  // ---- store: lane l holds o = ot*16+kg*4+r, px = lane&15 (coalesced 64B) ----
#pragma unroll
  for (int ot = 0; ot < 4; ++ot) {
#pragma unroll
    for (int pt = 0; pt < 4; ++pt) {
      int o = ot * 16 + kg * 4;
      int h = h0 + w4 + pt;
      float* op = out + ((size_t)(b * OO + o) * HH + h) * WW + w0 + px;
#pragma unroll
      for (int r = 0; r < 4; ++r)
        op[(size_t)r * HH * WW] = outacc[ot][pt][r];
    }
  }
}

extern "C" void kernel_launch(void* const* d_in, const int* in_sizes, int n_in,
                              void* d_out, int out_size, void* d_ws, size_t ws_size,
                              hipStream_t stream) {
  const float* x  = (const float*)d_in[0];
  const float* We = (const float*)d_in[1];
  const float* be = (const float*)d_in[2];
  const float* W1 = (const float*)d_in[3];
  const float* b1 = (const float*)d_in[4];
  const float* W2 = (const float*)d_in[5];
  const float* b2 = (const float*)d_in[6];
  float* out = (float*)d_out;

  float* probs = (float*)d_ws;                                  // 16 KB
  unsigned short* wpk = (unsigned short*)((char*)d_ws + 16384); // 576 KB bf16 packed weights

  gate_kernel<<<dim3(BB * NP * NP), dim3(256), 0, stream>>>(x, W1, b1, W2, b2, probs);
  pack_kernel<<<dim3((EE * 9 * OO * CC + 255) / 256), dim3(256), 0, stream>>>(We, wpk);
  conv_moe<<<dim3(NP * NP, BB), dim3(256), 0, stream>>>(x, wpk, be, probs, out);
}